// Round 15
// baseline (161.615 us; speedup 1.0000x reference)
//
#include <hip/hip_runtime.h>
#include <cmath>

#define BATCH 32768
#define DIM   128
#define HID   512
#define NPAD  2048     // 64 transformed dims * 32 (29 coeffs padded to 32)

typedef __attribute__((ext_vector_type(8))) _Float16 half8;
typedef __attribute__((ext_vector_type(8))) short   short8v;
typedef __attribute__((ext_vector_type(4))) float   f32x4;
typedef unsigned short u16;

// ---------------------------------------------------------------------------
// FL layout: off(r,k) = ((kt*(R/16) + (r>>4))*64 + ((r&15)|(((k&31)>>3)<<4)))*8 + (k&7)
// v15 gemm3: m201-analog 8-phase 256x256 schedule. 512 thr = 8 waves (2M x 4N),
// per-wave 128x64, acc[8][4]. A AND B staged via global_load_lds (no register
// vmem in mainloop -> exact vmcnt). Iteration = 2 K-tiles (64KB tile-pair),
// 8 staging ops/thread/iter (op p issued in phase p, consumed one full
// iteration later). 2 barriers + 2 vmcnt(4) per iteration; never 0 until the
// final half. setprio(1) around MFMA clusters (T5; pays on 8-phase, m218b).
// Race: ph0 vwait(4) retires ops0-3 (B+A kh0 of this iter); barrier after it;
// readers' lgkm drained before their barrier arrival; DMAs for i+1 (other
// buffer) issue only post-barrier.  gemm1/2: proven v10 kernels unchanged.
// ---------------------------------------------------------------------------

__device__ __forceinline__ u16 f2h(float f) {
  _Float16 h = (_Float16)f;
  union { _Float16 h; u16 u; } v; v.h = h; return v.u;
}

__device__ __forceinline__ void async16(const void* g, void* l) {
  __builtin_amdgcn_global_load_lds(
      (const __attribute__((address_space(1))) void*)g,
      (__attribute__((address_space(3))) void*)l, 16, 0, 0);
}

__device__ __forceinline__ void vwait4()  { asm volatile("s_waitcnt vmcnt(4)" ::: "memory"); }
__device__ __forceinline__ void vwait0()  { asm volatile("s_waitcnt vmcnt(0)" ::: "memory"); }
__device__ __forceinline__ void vwaitN(int n) {   // compile-time after unroll (v10 path)
  switch (n) {
    case 0:  asm volatile("s_waitcnt vmcnt(0)"  ::: "memory"); break;
    case 2:  asm volatile("s_waitcnt vmcnt(2)"  ::: "memory"); break;
    case 6:  asm volatile("s_waitcnt vmcnt(6)"  ::: "memory"); break;
    case 8:  asm volatile("s_waitcnt vmcnt(8)"  ::: "memory"); break;
    default: asm volatile("s_waitcnt vmcnt(12)" ::: "memory"); break;
  }
}

// T1: bijective XCD-aware block swizzle (requires nwg % 8 == 0)
__device__ __forceinline__ int xcd_swz(int bid, int nwg) {
  int cpx = nwg >> 3;
  return (bid & 7) * cpx + (bid >> 3);
}

// ---------------- merged prep kernel (produce FL f16 operands) ----------------

__global__ __launch_bounds__(256) void prep_all_v15(
    const float* __restrict__ z, const float* __restrict__ W1, const float* __restrict__ W2,
    const float* __restrict__ W3, const float* __restrict__ b3,
    u16* __restrict__ zh, u16* __restrict__ W1h, u16* __restrict__ W2h,
    u16* __restrict__ W3h, float* __restrict__ b3p) {
  const int bid = blockIdx.x;
  if (bid < 1024) {                                // za: 2*2048*64 lane-frags
    int id = bid * 256 + threadIdx.x;
    int l = id & 63, mb = (id >> 6) & 2047, kt = id >> 17;
    int r = mb * 16 + (l & 15);
    int k0 = kt * 32 + ((l >> 4) << 3);            // < 64: masked first half only
    const float* src = z + (size_t)r * DIM + k0;
    short8v H;
#pragma unroll
    for (int j = 0; j < 8; ++j) H[j] = (short)f2h(src[j]);
    *(short8v*)(zh + (size_t)id * 8) = H;
  } else if (bid < 1168) {                         // W1 (4096) + W2 (32768) frags
    int id = (bid - 1024) * 256 + threadIdx.x;
    if (id < 4096) {                               // W1: R=512, K=64 (first 64 cols)
      int l = id & 63, mb = (id >> 6) & 31, kt = id >> 11;
      int r = mb * 16 + (l & 15);
      int k0 = kt * 32 + ((l >> 4) << 3);
      const float* src = W1 + (size_t)r * DIM + k0;
      short8v H;
#pragma unroll
      for (int j = 0; j < 8; ++j) H[j] = (short)f2h(src[j]);
      *(short8v*)(W1h + (size_t)id * 8) = H;
    } else {                                       // W2: R=512, K=512
      int id2 = id - 4096;
      int l = id2 & 63, mb = (id2 >> 6) & 31, kt = id2 >> 11;
      int r = mb * 16 + (l & 15);
      int k0 = kt * 32 + ((l >> 4) << 3);
      const float* src = W2 + (size_t)r * HID + k0;
      short8v H;
#pragma unroll
      for (int j = 0; j < 8; ++j) H[j] = (short)f2h(src[j]);
      *(short8v*)(W2h + (size_t)id2 * 8) = H;
    }
  } else if (bid < 1680) {                         // W3: R=2048, K=512
    int id = (bid - 1168) * 256 + threadIdx.x;
    int l = id & 63, mb = (id >> 6) & 127, kt = id >> 13;
    int n = mb * 16 + (l & 15);
    int k0 = kt * 32 + ((l >> 4) << 3);
    int g = n >> 5, kk = n & 31;
    short8v H;
    if (kk < 29) {
      const float* src = W3 + ((size_t)((g + 64) * 29 + kk)) * HID + k0;
#pragma unroll
      for (int j = 0; j < 8; ++j) H[j] = (short)f2h(src[j]);
    } else {
#pragma unroll
      for (int j = 0; j < 8; ++j) H[j] = 0;
    }
    *(short8v*)(W3h + (size_t)id * 8) = H;
  } else {                                         // b3p: 2048
    int n = (bid - 1680) * 256 + threadIdx.x;
    int g = n >> 5, kk = n & 31;
    b3p[n] = (kk < 29) ? b3[(g + 64) * 29 + kk] : 0.f;
  }
}

// ------------- v10 mainloop (proven) for gemm1/gemm2: BM=BN=128, 4 waves -------------

__device__ __forceinline__ void stageA_v15(const u16* __restrict__ A, size_t ab, u16* Lb, int t) {
  async16(A + ab + t * 8,         Lb + t * 8);
  async16(A + ab + (t + 256) * 8, Lb + (t + 256) * 8);
}

template<int NKT>
__device__ __forceinline__ void gemm_mainloop_v15r(
    const u16* __restrict__ A, const u16* __restrict__ B,
    int a_mb0, int a_rs16, int b_nb0, int b_rs16,
    u16* LDS, f32x4 acc[4][4]) {
  const int t = threadIdx.x;
  const int lane = t & 63;
  const int wv = t >> 6;
  const int wr = wv >> 1, wc = wv & 1;
  const size_t aStep = (size_t)a_rs16 * 512;
  const size_t bStep = (size_t)b_rs16 * 512;
  const size_t ab0 = (size_t)a_mb0 * 512;
  const u16* Bp = B + (((size_t)(b_nb0 + wc * 4)) * 64 + lane) * 8;

  half8 b[3][4];
#pragma unroll
  for (int nf = 0; nf < 4; ++nf) b[0][nf] = *(const half8*)(Bp + nf * 512);
  if (NKT > 1) {
#pragma unroll
    for (int nf = 0; nf < 4; ++nf) b[1][nf] = *(const half8*)(Bp + bStep + nf * 512);
  }
  stageA_v15(A, ab0, LDS, t);
  if (NKT > 1) stageA_v15(A, ab0 + aStep, LDS + 4096, t);

#pragma unroll
  for (int kt = 0; kt < NKT; ++kt) {
    if (kt + 2 < NKT) {
#pragma unroll
      for (int nf = 0; nf < 4; ++nf)
        b[(kt + 2) % 3][nf] = *(const half8*)(Bp + (size_t)(kt + 2) * bStep + nf * 512);
      stageA_v15(A, ab0 + (size_t)(kt + 2) * aStep, LDS + ((kt + 2) & 3) * 4096, t);
    }
    int n_after = (kt == 0) ? ((NKT > 1 ? 2 : 0) + (NKT > 2 ? 6 : 0))
                            : (((kt + 1 < NKT) ? 6 : 0) + ((kt + 2 < NKT) ? 6 : 0));
    vwaitN(n_after);
    __builtin_amdgcn_s_barrier();
    __builtin_amdgcn_sched_barrier(0);
    half8 a[4];
#pragma unroll
    for (int mf = 0; mf < 4; ++mf)
      a[mf] = *(const half8*)(LDS + (kt & 3) * 4096 + ((wr * 4 + mf) * 64 + lane) * 8);
#pragma unroll
    for (int mf = 0; mf < 4; ++mf)
#pragma unroll
      for (int nf = 0; nf < 4; ++nf)
        acc[mf][nf] = __builtin_amdgcn_mfma_f32_16x16x32_f16(a[mf], b[kt % 3][nf], acc[mf][nf], 0, 0, 0);
  }
}

template<int NKT>
__global__ __launch_bounds__(256, 3) void gemm_relu_v15(
    const u16* __restrict__ A, const u16* __restrict__ B,
    const float* __restrict__ bias, u16* __restrict__ C, int a_rs16) {
  __shared__ __align__(16) u16 LDS[16384];
  const int bid = xcd_swz(blockIdx.x, gridDim.x);
  const int nt = bid & 3;                         // N = 512
  const int mt = bid >> 2;
  const int m0 = mt << 7, n0 = nt << 7;
  f32x4 zero = {0.f, 0.f, 0.f, 0.f};
  f32x4 acc[4][4];
#pragma unroll
  for (int i = 0; i < 4; ++i)
#pragma unroll
    for (int j = 0; j < 4; ++j) acc[i][j] = zero;

  gemm_mainloop_v15r<NKT>(A, B, m0 >> 4, a_rs16, n0 >> 4, 32, LDS, acc);

  const int lane = threadIdx.x & 63;
  const int wv = threadIdx.x >> 6;
  const int wr = wv >> 1, wc = wv & 1;
#pragma unroll
  for (int mf = 0; mf < 4; ++mf) {
#pragma unroll
    for (int nf = 0; nf < 4; ++nf) {
      int col = n0 + wc * 64 + nf * 16 + (lane & 15);
      float bv = bias[col];
#pragma unroll
      for (int r = 0; r < 4; ++r) {
        int row = m0 + wr * 64 + mf * 16 + (lane >> 4) * 4 + r;
        float v = fmaxf(acc[mf][nf][r] + bv, 0.f);
        int ktO = col >> 5, mbO = row >> 4;
        int lO = (row & 15) | (((col >> 3) & 3) << 4);
        int jO = col & 7;
        size_t off = (((size_t)ktO * (BATCH >> 4) + mbO) * 64 + lO) * 8 + jO;
        C[off] = f2h(v);
      }
    }
  }
}

// ---------------- RQS spline (per (row, dim)) ----------------

__device__ __forceinline__ void rqs(float xin, const float uw[10], const float uh[10], const float ud9[9],
                                    float& yv, float& ldv) {
  float mw = uw[0];
#pragma unroll
  for (int i = 1; i < 10; ++i) mw = fmaxf(mw, uw[i]);
  float ew[10]; float sw = 0.f;
#pragma unroll
  for (int i = 0; i < 10; ++i) { ew[i] = __expf(uw[i] - mw); sw += ew[i]; }
  float invw = 0.99f / sw;
  float cw[11]; cw[0] = -5.f;
  {
    float run = 0.f;
#pragma unroll
    for (int i = 0; i < 10; ++i) { run += 0.001f + invw * ew[i]; cw[i + 1] = 10.f * run - 5.f; }
  }
  cw[10] = 5.f;
  float mh = uh[0];
#pragma unroll
  for (int i = 1; i < 10; ++i) mh = fmaxf(mh, uh[i]);
  float eh[10]; float sh = 0.f;
#pragma unroll
  for (int i = 0; i < 10; ++i) { eh[i] = __expf(uh[i] - mh); sh += eh[i]; }
  float invh = 0.99f / sh;
  float ch[11]; ch[0] = -5.f;
  {
    float run = 0.f;
#pragma unroll
    for (int i = 0; i < 10; ++i) { run += 0.001f + invh * eh[i]; ch[i + 1] = 10.f * run - 5.f; }
  }
  ch[10] = 5.f;
  float dv[11]; dv[0] = 1.f; dv[10] = 1.f;
#pragma unroll
  for (int i = 0; i < 9; ++i) {
    float x = ud9[i];
    float sp = fmaxf(x, 0.f) + __logf(1.f + __expf(-fabsf(x)));
    dv[i + 1] = 0.001f + sp;
  }

  float xc = fminf(fmaxf(xin, -5.f), 5.f);
  int b = 0;
#pragma unroll
  for (int j = 1; j <= 10; ++j) b += (cw[j] <= xc) ? 1 : 0;
  b = (b > 9) ? 9 : b;

  float wk = cw[1] - cw[0], cwk = cw[0], hk = ch[1] - ch[0], chk = ch[0], dk = dv[0], dk1 = dv[1];
#pragma unroll
  for (int j = 1; j < 10; ++j) {
    if (j == b) { wk = cw[j + 1] - cw[j]; cwk = cw[j]; hk = ch[j + 1] - ch[j]; chk = ch[j]; dk = dv[j]; dk1 = dv[j + 1]; }
  }

  float th = (xc - cwk) / wk;
  float sr = hk / wk;
  float omth = 1.f - th;
  float tm = th * omth;
  float den = sr + (dk + dk1 - 2.f * sr) * tm;
  float num = hk * (sr * th * th + dk * tm);
  float y = chk + num / den;
  float ld = __logf(sr * sr * (dk1 * th * th + 2.f * sr * tm + dk * omth * omth)) - 2.f * __logf(den);
  bool inside = (xin >= -5.f) && (xin <= 5.f);
  yv = inside ? y : xin;
  ldv = inside ? ld : 0.f;
  if (!isfinite(yv)) yv = 0.f;
}

// ---------------- GEMM3: 256x256 8-phase + spline epilogue ----------------
// LDS buffer j (32768 u16 = 64KB): [B kt0 8K][A kt0 8K][B kt1 8K][A kt1 8K] u16.
// Staging op p (0..7): dest = buf2 + p*4096 + t*8 ; 8KB per op (512 thr x 16B).

__global__ __launch_bounds__(512, 1) void gemm3_8ph_v15(
    const u16* __restrict__ A, const u16* __restrict__ B,
    const float* __restrict__ b3p, const float* __restrict__ z,
    float* __restrict__ xout, float* __restrict__ partial) {
  __shared__ __align__(16) char SMEM[131072];     // 2 x 64KB tile-pair buffers; PT aliases
  u16* LDS = (u16*)SMEM;
  float* PTf = (float*)SMEM;                      // [64][265] = 67840 B
  const int bid = xcd_swz(blockIdx.x, gridDim.x);
  const int nt = bid & 7;                         // N = 2048 -> 8 n-tiles of 256
  const int mt = bid >> 3;                        // 128 m-tiles of 256
  const int m0 = mt << 8, n0 = nt << 8;
  const int mb0 = m0 >> 4, nb0 = n0 >> 4;
  const int t = threadIdx.x;
  const int lane = t & 63;
  const int wid = t >> 6;
  const int wr = wid >> 2;                        // 0..1 (row half: 128 rows)
  const int wc = wid & 3;                         // 0..3 (col quarter: 64 cols)
  constexpr int NITER = 8;                        // 16 K-tiles, 2 per iteration
  const size_t aStep = (size_t)(BATCH >> 4) * 512;   // u16 per A K-tile
  const size_t bStep = (size_t)(NPAD  >> 4) * 512;   // u16 per B K-tile

  f32x4 zero = {0.f, 0.f, 0.f, 0.f};
  f32x4 acc[8][4];
#pragma unroll
  for (int i = 0; i < 8; ++i)
#pragma unroll
    for (int j = 0; j < 4; ++j) acc[i][j] = zero;

  // --- staging op p for K-tile pair starting at kt0, into buffer bufsel ---
  // p: 0,1 = B kt0 halves; 2,3 = A kt0; 4,5 = B kt1; 6,7 = A kt1.
#define STAGE_OP(p, kt0_, bufsel)                                                        \
  {                                                                                      \
    const int kt_ = (kt0_) + ((p) >> 2);                                                 \
    const int h_ = (p) & 1;                                                              \
    u16* dst_ = LDS + (bufsel) * 32768 + (p) * 4096 + t * 8;                             \
    if (((p) & 2) == 0)                                                                  \
      async16(B + ((size_t)kt_ * bStep) + (size_t)nb0 * 512 + h_ * 4096 + t * 8, dst_);  \
    else                                                                                 \
      async16(A + ((size_t)kt_ * aStep) + (size_t)mb0 * 512 + h_ * 4096 + t * 8, dst_);  \
  }

  // prologue: full tile-pair for iteration 0 into buffer 0 (ops 0..7 in order)
#pragma unroll
  for (int p = 0; p < 8; ++p) STAGE_OP(p, 0, 0)

#pragma unroll
  for (int i = 0; i < NITER; ++i) {
    u16* buf = LDS + (i & 1) * 32768;
    const int b2 = (i + 1) & 1;
    const bool more = (i + 1 < NITER);
    const int ktn = 2 * (i + 1);

    // ===== half kh=0 (K-tile 2i) =====
    vwait4();                                      // ops 0-3 of iter i retired (4 left: ops 4-7)
    __builtin_amdgcn_s_barrier();
    __builtin_amdgcn_sched_barrier(0);
    {
      half8 b0[4];
#pragma unroll
      for (int nf = 0; nf < 4; ++nf)
        b0[nf] = *(const half8*)(buf + ((wc * 4 + nf) * 64 + lane) * 8);
#pragma unroll
      for (int q = 0; q < 4; ++q) {
        half8 a0 = *(const half8*)(buf + 8192 + ((wr * 8 + 2 * q + 0) * 64 + lane) * 8);
        half8 a1 = *(const half8*)(buf + 8192 + ((wr * 8 + 2 * q + 1) * 64 + lane) * 8);
        if (more) { STAGE_OP(q, ktn, b2) }         // ops 0..3 for iter i+1
        __builtin_amdgcn_s_setprio(1);
#pragma unroll
        for (int nf = 0; nf < 4; ++nf) {
          acc[2 * q + 0][nf] = __builtin_amdgcn_mfma_f32_16x16x32_f16(a0, b0[nf], acc[2 * q + 0][nf], 0, 0, 0);
          acc[2 * q + 1][nf] = __builtin_amdgcn_mfma_f32_16x16x32_f16(a1, b0[nf], acc[2 * q + 1][nf], 0, 0, 0);
        }
        __builtin_amdgcn_s_setprio(0);
      }
    }

    // ===== half kh=1 (K-tile 2i+1) =====
    if (more) vwait4(); else vwait0();             // ops 4-7 of iter i retired
    __builtin_amdgcn_s_barrier();
    __builtin_amdgcn_sched_barrier(0);
    {
      half8 b1[4];
#pragma unroll
      for (int nf = 0; nf < 4; ++nf)
        b1[nf] = *(const half8*)(buf + 16384 + ((wc * 4 + nf) * 64 + lane) * 8);
#pragma unroll
      for (int q = 0; q < 4; ++q) {
        half8 a0 = *(const half8*)(buf + 24576 + ((wr * 8 + 2 * q + 0) * 64 + lane) * 8);
        half8 a1 = *(const half8*)(buf + 24576 + ((wr * 8 + 2 * q + 1) * 64 + lane) * 8);
        if (more) { STAGE_OP(q + 4, ktn, b2) }     // ops 4..7 for iter i+1
        __builtin_amdgcn_s_setprio(1);
#pragma unroll
        for (int nf = 0; nf < 4; ++nf) {
          acc[2 * q + 0][nf] = __builtin_amdgcn_mfma_f32_16x16x32_f16(a0, b1[nf], acc[2 * q + 0][nf], 0, 0, 0);
          acc[2 * q + 1][nf] = __builtin_amdgcn_mfma_f32_16x16x32_f16(a1, b1[nf], acc[2 * q + 1][nf], 0, 0, 0);
        }
        __builtin_amdgcn_s_setprio(0);
      }
    }
  }
#undef STAGE_OP

  // ---------------- spline epilogue: 4 stripes of 64 rows ----------------
  // PT[64][265]: row stride 265 (mod 32 = 9), dim-group stride 33 -> ~2-way max.
#pragma unroll
  for (int s = 0; s < 4; ++s) {
    __syncthreads();
    if (wr == (s >> 1)) {
#pragma unroll
      for (int mfl = 0; mfl < 4; ++mfl) {
        const int mf = (s & 1) * 4 + mfl;
#pragma unroll
        for (int nf = 0; nf < 4; ++nf)
#pragma unroll
          for (int r = 0; r < 4; ++r) {
            int col = wc * 64 + nf * 16 + (lane & 15);        // 0..255
            int rowl = mfl * 16 + (lane >> 4) * 4 + r;        // 0..63
            PTf[rowl * 265 + (col >> 5) * 33 + (col & 31)] = acc[mf][nf][r];
          }
      }
    }
    __syncthreads();

    const int row = t >> 3;        // 0..63
    const int g = t & 7;           // dim group 0..7
    const int grow = m0 + s * 64 + row;
    const int gdim = nt * 8 + g;   // global transformed-dim 0..63
    const float* pr = PTf + row * 265 + g * 33;
    const float* bb = b3p + n0 + g * 32;
    float uw[10], uh[10], ud9[9];
#pragma unroll
    for (int i = 0; i < 10; ++i) uw[i] = pr[i] + bb[i];
#pragma unroll
    for (int i = 0; i < 10; ++i) uh[i] = pr[10 + i] + bb[10 + i];
#pragma unroll
    for (int i = 0; i < 9; ++i) ud9[i] = pr[20 + i] + bb[20 + i];

    float xin = z[(long)grow * DIM + 64 + gdim];
    float yv, ldv;
    rqs(xin, uw, uh, ud9, yv, ldv);

    xout[(long)grow * DIM + 64 + gdim] = yv;

    float sld = ldv;
    sld += __shfl_down(sld, 1);
    sld += __shfl_down(sld, 2);
    sld += __shfl_down(sld, 4);
    if (g == 0) partial[(size_t)nt * BATCH + grow] = sld;
  }
}

// ---------------- pass-through copy + logdet reduce ----------------

__global__ __launch_bounds__(256) void copy_first_v15(const float* __restrict__ z, float* __restrict__ xout) {
  int id = blockIdx.x * 256 + threadIdx.x;        // < 32768*16
  int m = id >> 4, c4 = id & 15;
  const float4 v = *(const float4*)(z + (long)m * DIM + c4 * 4);
  *(float4*)(xout + (long)m * DIM + c4 * 4) = v;
}

__global__ __launch_bounds__(256) void reduce_ld_v15(const float* __restrict__ partial, float* __restrict__ ldout) {
  int row = blockIdx.x * 256 + threadIdx.x;
  float s = 0.f;
#pragma unroll
  for (int i = 0; i < 8; ++i) s += partial[(long)i * BATCH + row];
  if (!isfinite(s)) s = 0.f;
  ldout[row] = s;
}

// ---------------- launch ----------------

extern "C" void kernel_launch(void* const* d_in, const int* in_sizes, int n_in,
                              void* d_out, int out_size, void* d_ws, size_t ws_size,
                              hipStream_t stream) {
  const float* z  = (const float*)d_in[0];
  const float* W1 = (const float*)d_in[1];
  const float* b1 = (const float*)d_in[2];
  const float* W2 = (const float*)d_in[3];
  const float* b2 = (const float*)d_in[4];
  const float* W3 = (const float*)d_in[5];
  const float* b3 = (const float*)d_in[6];
  float* xout  = (float*)d_out;
  float* ldout = xout + (size_t)BATCH * DIM;

  char* ws = (char*)d_ws;
  u16* W1h = (u16*)ws;  ws += (size_t)512 * 64 * 2;
  u16* W2h = (u16*)ws;  ws += (size_t)512 * 512 * 2;
  u16* W3h = (u16*)ws;  ws += (size_t)NPAD * HID * 2;
  float* b3p = (float*)ws; ws += (size_t)NPAD * 4;
  // za and part alias (disjoint lifetimes: za consumed by gemm1; part written by gemm3)
  u16* zah  = (u16*)ws;
  float* part = (float*)ws; ws += (size_t)BATCH * 64 * 2;   // 4 MB (part needs 1 MB)
  u16* h1h = (u16*)ws;  ws += (size_t)BATCH * HID * 2;
  u16* h2h = (u16*)ws;  ws += (size_t)BATCH * HID * 2;

  prep_all_v15<<<1688, 256, 0, stream>>>(z, W1, W2, W3, b3, zah, W1h, W2h, W3h, b3p);

  // GEMM1: A = za (R=BATCH, rs16=2048), K=64 (NKT=2)
  gemm_relu_v15<2><<<(BATCH / 128) * 4, 256, 0, stream>>>(zah, W1h, b1, h1h, BATCH >> 4);
  // GEMM2: A = h1 (R=BATCH), K=512 (NKT=16)
  gemm_relu_v15<16><<<(BATCH / 128) * 4, 256, 0, stream>>>(h1h, W2h, b2, h2h, BATCH >> 4);
  // GEMM3 + spline: 256x256 tiles -> (32768/256) x (2048/256) = 1024 blocks, 512 threads
  gemm3_8ph_v15<<<(BATCH / 256) * (NPAD / 256), 512, 0, stream>>>(h2h, W3h, b3p, z, xout, part);

  copy_first_v15<<<(BATCH * 16) / 256, 256, 0, stream>>>(z, xout);
  reduce_ld_v15<<<BATCH / 256, 256, 0, stream>>>(part, ldout);
}

// Round 16
// 146.798 us; speedup vs baseline: 1.1009x; 1.1009x over previous
//
#include <hip/hip_runtime.h>
#include <cmath>

#define BATCH 32768
#define DIM   128
#define HID   512
#define NPAD  2048     // 64 transformed dims * 32 (29 coeffs padded to 32)

typedef __attribute__((ext_vector_type(8))) _Float16 half8;
typedef __attribute__((ext_vector_type(8))) short   short8v;
typedef __attribute__((ext_vector_type(4))) float   f32x4;
typedef unsigned short u16;

// ---------------------------------------------------------------------------
// Fragment-linear (FL) layout for a [R][K] f16 operand (R%16==0, K%32==0):
//   off(r,k) = ((kt*(R/16) + (r>>4))*64 + ((r&15) | (((k&31)>>3)<<4)))*8 + (k&7)
// v16 = v10 (empirical optimum of 9 structural variants, 105us gemm3):
//   A via global_load_lds, 4 x 8KB buffers, distance 2, counted vmcnt
//   (A-only counting - only pinned DMAs enter the arithmetic), raw s_barrier;
//   B (weights, L2-hot) global->VGPR, 3-deep rotation, distance 2;
//   launch_bounds(256,3) (NOT 4: v9 showed (256,4) spills breg to scratch).
// Plus: copy_first folded into prep_all (one fewer launch, overlapped copy).
// ---------------------------------------------------------------------------

__device__ __forceinline__ u16 f2h(float f) {
  _Float16 h = (_Float16)f;
  union { _Float16 h; u16 u; } v; v.h = h; return v.u;
}

__device__ __forceinline__ void async16(const void* g, void* l) {
  __builtin_amdgcn_global_load_lds(
      (const __attribute__((address_space(1))) void*)g,
      (__attribute__((address_space(3))) void*)l, 16, 0, 0);
}

__device__ __forceinline__ void vwait(int n) {   // n is compile-time after unroll
  switch (n) {
    case 0:  asm volatile("s_waitcnt vmcnt(0)"  ::: "memory"); break;
    case 2:  asm volatile("s_waitcnt vmcnt(2)"  ::: "memory"); break;
    case 6:  asm volatile("s_waitcnt vmcnt(6)"  ::: "memory"); break;
    case 8:  asm volatile("s_waitcnt vmcnt(8)"  ::: "memory"); break;
    default: asm volatile("s_waitcnt vmcnt(12)" ::: "memory"); break;
  }
}

// T1: bijective XCD-aware block swizzle (requires nwg % 8 == 0)
__device__ __forceinline__ int xcd_swz(int bid, int nwg) {
  int cpx = nwg >> 3;
  return (bid & 7) * cpx + (bid >> 3);
}

// -------- merged prep kernel (FL f16 operands) + passthrough x-copy --------

__global__ __launch_bounds__(256) void prep_all_v16(
    const float* __restrict__ z, const float* __restrict__ W1, const float* __restrict__ W2,
    const float* __restrict__ W3, const float* __restrict__ b3,
    u16* __restrict__ zh, u16* __restrict__ W1h, u16* __restrict__ W2h,
    u16* __restrict__ W3h, float* __restrict__ b3p, float* __restrict__ xout) {
  const int bid = blockIdx.x;
  if (bid < 1024) {                                // za: 2*2048*64 lane-frags
    int id = bid * 256 + threadIdx.x;
    int l = id & 63, mb = (id >> 6) & 2047, kt = id >> 17;
    int r = mb * 16 + (l & 15);
    int k0 = kt * 32 + ((l >> 4) << 3);            // < 64: masked first half only
    const float* src = z + (size_t)r * DIM + k0;
    short8v H;
#pragma unroll
    for (int j = 0; j < 8; ++j) H[j] = (short)f2h(src[j]);
    *(short8v*)(zh + (size_t)id * 8) = H;
  } else if (bid < 1168) {                         // W1 (4096) + W2 (32768) frags
    int id = (bid - 1024) * 256 + threadIdx.x;
    if (id < 4096) {                               // W1: R=512, K=64 (first 64 cols)
      int l = id & 63, mb = (id >> 6) & 31, kt = id >> 11;
      int r = mb * 16 + (l & 15);
      int k0 = kt * 32 + ((l >> 4) << 3);
      const float* src = W1 + (size_t)r * DIM + k0;
      short8v H;
#pragma unroll
      for (int j = 0; j < 8; ++j) H[j] = (short)f2h(src[j]);
      *(short8v*)(W1h + (size_t)id * 8) = H;
    } else {                                       // W2: R=512, K=512
      int id2 = id - 4096;
      int l = id2 & 63, mb = (id2 >> 6) & 31, kt = id2 >> 11;
      int r = mb * 16 + (l & 15);
      int k0 = kt * 32 + ((l >> 4) << 3);
      const float* src = W2 + (size_t)r * HID + k0;
      short8v H;
#pragma unroll
      for (int j = 0; j < 8; ++j) H[j] = (short)f2h(src[j]);
      *(short8v*)(W2h + (size_t)id2 * 8) = H;
    }
  } else if (bid < 1680) {                         // W3: R=2048, K=512
    int id = (bid - 1168) * 256 + threadIdx.x;
    int l = id & 63, mb = (id >> 6) & 127, kt = id >> 13;
    int n = mb * 16 + (l & 15);
    int k0 = kt * 32 + ((l >> 4) << 3);
    int g = n >> 5, kk = n & 31;
    short8v H;
    if (kk < 29) {
      const float* src = W3 + ((size_t)((g + 64) * 29 + kk)) * HID + k0;
#pragma unroll
      for (int j = 0; j < 8; ++j) H[j] = (short)f2h(src[j]);
    } else {
#pragma unroll
      for (int j = 0; j < 8; ++j) H[j] = 0;
    }
    *(short8v*)(W3h + (size_t)id * 8) = H;
  } else if (bid < 1688) {                         // b3p: 2048
    int n = (bid - 1680) * 256 + threadIdx.x;
    int g = n >> 5, kk = n & 31;
    b3p[n] = (kk < 29) ? b3[(g + 64) * 29 + kk] : 0.f;
  } else {                                         // passthrough copy: x[:, :64] = z[:, :64]
    int id = (bid - 1688) * 256 + threadIdx.x;     // < 32768*16
    int m = id >> 4, c4 = id & 15;
    const float4 v = *(const float4*)(z + (size_t)m * DIM + c4 * 4);
    *(float4*)(xout + (size_t)m * DIM + c4 * 4) = v;
  }
}

// ------------- v16 mainloop: BM=BN=128, BK=32, 4 waves (2x2) -------------

__device__ __forceinline__ void stageA_v16(const u16* __restrict__ A, size_t ab, u16* Lb, int t) {
  async16(A + ab + t * 8,         Lb + t * 8);
  async16(A + ab + (t + 256) * 8, Lb + (t + 256) * 8);
}

template<int NKT>
__device__ __forceinline__ void gemm_mainloop_v16(
    const u16* __restrict__ A, const u16* __restrict__ B,
    int a_rb0, int a_rs16, int b_rb0, int b_rs16,
    u16* LDS, f32x4 acc[4][4]) {
  const int t = threadIdx.x;
  const int lane = t & 63;
  const int wv = t >> 6;
  const int wr = wv >> 1, wc = wv & 1;
  const size_t aStep = (size_t)a_rs16 * 512;       // u16 per K-tile
  const size_t bStep = (size_t)b_rs16 * 512;
  const size_t ab0 = (size_t)a_rb0 * 512;
  const u16* Bp = B + (((size_t)(b_rb0 + wc * 4)) * 64 + lane) * 8;

  half8 breg[3][4];
  // prologue: B(0), B(1) then A(0), A(1)
#pragma unroll
  for (int nf = 0; nf < 4; ++nf) breg[0][nf] = *(const half8*)(Bp + nf * 512);
  if (NKT > 1) {
#pragma unroll
    for (int nf = 0; nf < 4; ++nf) breg[1][nf] = *(const half8*)(Bp + bStep + nf * 512);
  }
  stageA_v16(A, ab0, LDS, t);
  if (NKT > 1) stageA_v16(A, ab0 + aStep, LDS + 4096, t);

#pragma unroll
  for (int kt = 0; kt < NKT; ++kt) {
    if (kt + 2 < NKT) {
#pragma unroll
      for (int nf = 0; nf < 4; ++nf)
        breg[(kt + 2) % 3][nf] = *(const half8*)(Bp + (size_t)(kt + 2) * bStep + nf * 512);
      stageA_v16(A, ab0 + (size_t)(kt + 2) * aStep, LDS + ((kt + 2) & 3) * 4096, t);
    }
    // in-order retirement: wait until A(kt) (and thus B(kt), older) retired.
    int n_after = (kt == 0) ? ((NKT > 1 ? 2 : 0) + (NKT > 2 ? 6 : 0))
                            : (((kt + 1 < NKT) ? 6 : 0) + ((kt + 2 < NKT) ? 6 : 0));
    vwait(n_after);
    __builtin_amdgcn_s_barrier();                  // all waves see A(kt) in LDS
    __builtin_amdgcn_sched_barrier(0);             // pin ds_reads after barrier
    half8 a[4];
#pragma unroll
    for (int mf = 0; mf < 4; ++mf)
      a[mf] = *(const half8*)(LDS + (kt & 3) * 4096 + ((wr * 4 + mf) * 64 + lane) * 8);
#pragma unroll
    for (int mf = 0; mf < 4; ++mf)
#pragma unroll
      for (int nf = 0; nf < 4; ++nf)
        acc[mf][nf] = __builtin_amdgcn_mfma_f32_16x16x32_f16(a[mf], breg[kt % 3][nf], acc[mf][nf], 0, 0, 0);
  }
}

// ---------------- GEMM + bias + relu -> f16 (FL output, R=BATCH) ----------------

template<int NKT>
__global__ __launch_bounds__(256, 3) void gemm_relu_v16(
    const u16* __restrict__ A, const u16* __restrict__ B,
    const float* __restrict__ bias, u16* __restrict__ C, int a_rs16) {
  __shared__ __align__(16) u16 LDS[16384];        // 32 KB: 4 x 8 KB A-buffers
  const int bid = xcd_swz(blockIdx.x, gridDim.x);
  const int nt = bid & 3;                         // N = 512
  const int mt = bid >> 2;
  const int m0 = mt << 7, n0 = nt << 7;
  f32x4 zero = {0.f, 0.f, 0.f, 0.f};
  f32x4 acc[4][4];
#pragma unroll
  for (int i = 0; i < 4; ++i)
#pragma unroll
    for (int j = 0; j < 4; ++j) acc[i][j] = zero;

  gemm_mainloop_v16<NKT>(A, B, m0 >> 4, a_rs16, n0 >> 4, 32, LDS, acc);

  const int lane = threadIdx.x & 63;
  const int wv = threadIdx.x >> 6;
  const int wr = wv >> 1, wc = wv & 1;
#pragma unroll
  for (int mf = 0; mf < 4; ++mf) {
#pragma unroll
    for (int nf = 0; nf < 4; ++nf) {
      int col = n0 + wc * 64 + nf * 16 + (lane & 15);
      float bv = bias[col];
#pragma unroll
      for (int r = 0; r < 4; ++r) {
        int row = m0 + wr * 64 + mf * 16 + (lane >> 4) * 4 + r;
        float v = fmaxf(acc[mf][nf][r] + bv, 0.f);
        // FL store (R=BATCH, rs16=2048)
        int ktO = col >> 5, mbO = row >> 4;
        int lO = (row & 15) | (((col >> 3) & 3) << 4);
        int jO = col & 7;
        size_t off = (((size_t)ktO * (BATCH >> 4) + mbO) * 64 + lO) * 8 + jO;
        C[off] = f2h(v);
      }
    }
  }
}

// ---------------- RQS spline (per (row, dim)) ----------------

__device__ __forceinline__ void rqs(float xin, const float uw[10], const float uh[10], const float ud9[9],
                                    float& yv, float& ldv) {
  float mw = uw[0];
#pragma unroll
  for (int i = 1; i < 10; ++i) mw = fmaxf(mw, uw[i]);
  float ew[10]; float sw = 0.f;
#pragma unroll
  for (int i = 0; i < 10; ++i) { ew[i] = __expf(uw[i] - mw); sw += ew[i]; }
  float invw = 0.99f / sw;
  float cw[11]; cw[0] = -5.f;
  {
    float run = 0.f;
#pragma unroll
    for (int i = 0; i < 10; ++i) { run += 0.001f + invw * ew[i]; cw[i + 1] = 10.f * run - 5.f; }
  }
  cw[10] = 5.f;
  float mh = uh[0];
#pragma unroll
  for (int i = 1; i < 10; ++i) mh = fmaxf(mh, uh[i]);
  float eh[10]; float sh = 0.f;
#pragma unroll
  for (int i = 0; i < 10; ++i) { eh[i] = __expf(uh[i] - mh); sh += eh[i]; }
  float invh = 0.99f / sh;
  float ch[11]; ch[0] = -5.f;
  {
    float run = 0.f;
#pragma unroll
    for (int i = 0; i < 10; ++i) { run += 0.001f + invh * eh[i]; ch[i + 1] = 10.f * run - 5.f; }
  }
  ch[10] = 5.f;
  float dv[11]; dv[0] = 1.f; dv[10] = 1.f;
#pragma unroll
  for (int i = 0; i < 9; ++i) {
    float x = ud9[i];
    float sp = fmaxf(x, 0.f) + __logf(1.f + __expf(-fabsf(x)));
    dv[i + 1] = 0.001f + sp;
  }

  float xc = fminf(fmaxf(xin, -5.f), 5.f);
  int b = 0;
#pragma unroll
  for (int j = 1; j <= 10; ++j) b += (cw[j] <= xc) ? 1 : 0;
  b = (b > 9) ? 9 : b;

  float wk = cw[1] - cw[0], cwk = cw[0], hk = ch[1] - ch[0], chk = ch[0], dk = dv[0], dk1 = dv[1];
#pragma unroll
  for (int j = 1; j < 10; ++j) {
    if (j == b) { wk = cw[j + 1] - cw[j]; cwk = cw[j]; hk = ch[j + 1] - ch[j]; chk = ch[j]; dk = dv[j]; dk1 = dv[j + 1]; }
  }

  float th = (xc - cwk) / wk;
  float sr = hk / wk;
  float omth = 1.f - th;
  float tm = th * omth;
  float den = sr + (dk + dk1 - 2.f * sr) * tm;
  float num = hk * (sr * th * th + dk * tm);
  float y = chk + num / den;
  float ld = __logf(sr * sr * (dk1 * th * th + 2.f * sr * tm + dk * omth * omth)) - 2.f * __logf(den);
  bool inside = (xin >= -5.f) && (xin <= 5.f);
  yv = inside ? y : xin;
  ldv = inside ? ld : 0.f;
  if (!isfinite(yv)) yv = 0.f;
}

// ---------------- GEMM3 fused with spline epilogue ----------------
// PT: row stride 132 f32 (== 4 mod 32), dim-group stride 33 => 2-way max (free).

__global__ __launch_bounds__(256, 3) void gemm3_spline_v16(
    const u16* __restrict__ A, const u16* __restrict__ B,
    const float* __restrict__ b3p, const float* __restrict__ z,
    float* __restrict__ xout, float* __restrict__ partial) {
  __shared__ __align__(16) char SMEM[33792];      // 4 x 8 KB A-staging, aliased with PT (33792 B)
  u16* LDS = (u16*)SMEM;
  float* PTf = (float*)SMEM;                      // [64][132]
  const int bid = xcd_swz(blockIdx.x, gridDim.x);
  const int nt = bid & 15;
  const int mt = bid >> 4;
  const int m0 = mt << 7, n0 = nt << 7;
  f32x4 zero = {0.f, 0.f, 0.f, 0.f};
  f32x4 acc[4][4];
#pragma unroll
  for (int i = 0; i < 4; ++i)
#pragma unroll
    for (int j = 0; j < 4; ++j) acc[i][j] = zero;

  gemm_mainloop_v16<16>(A, B, m0 >> 4, BATCH >> 4, n0 >> 4, NPAD >> 4, LDS, acc);

  const int t = threadIdx.x;
  const int lane = t & 63;
  const int wv = t >> 6;
  const int wr = wv >> 1, wc = wv & 1;
  const int gb = n0 >> 5;   // global transformed-dim base for this block (4 dims)

  for (int p = 0; p < 2; ++p) {
    __syncthreads();
    if (wr == p) {
#pragma unroll
      for (int mf = 0; mf < 4; ++mf)
#pragma unroll
        for (int nf = 0; nf < 4; ++nf)
#pragma unroll
          for (int r = 0; r < 4; ++r) {
            int cl = wc * 64 + nf * 16 + (lane & 15);         // local col 0..127
            int rowl = mf * 16 + (lane >> 4) * 4 + r;         // 0..63
            PTf[rowl * 132 + (cl >> 5) * 33 + (cl & 31)] = acc[mf][nf][r];
          }
    }
    __syncthreads();

    const int rl = t >> 2;          // 0..63
    const int g = t & 3;            // local dim 0..3
    const int row = p * 64 + rl;
    const int grow = m0 + row;
    const float* pr = PTf + rl * 132 + g * 33;
    const float* bb = b3p + n0 + g * 32;
    float uw[10], uh[10], ud9[9];
#pragma unroll
    for (int i = 0; i < 10; ++i) uw[i] = pr[i] + bb[i];
#pragma unroll
    for (int i = 0; i < 10; ++i) uh[i] = pr[10 + i] + bb[10 + i];
#pragma unroll
    for (int i = 0; i < 9; ++i) ud9[i] = pr[20 + i] + bb[20 + i];

    float xin = z[(long)grow * DIM + 64 + gb + g];
    float yv, ldv;
    rqs(xin, uw, uh, ud9, yv, ldv);

    xout[(long)grow * DIM + 64 + gb + g] = yv;

    float s = ldv;
    s += __shfl_down(s, 1);
    s += __shfl_down(s, 2);
    if (g == 0) partial[(long)nt * BATCH + grow] = s;
  }
}

// ---------------- logdet reduce ----------------

__global__ __launch_bounds__(256) void reduce_ld_v16(const float* __restrict__ partial, float* __restrict__ ldout) {
  int row = blockIdx.x * 256 + threadIdx.x;
  float s = 0.f;
#pragma unroll
  for (int i = 0; i < 16; ++i) s += partial[(long)i * BATCH + row];
  if (!isfinite(s)) s = 0.f;
  ldout[row] = s;
}

// ---------------- launch ----------------

extern "C" void kernel_launch(void* const* d_in, const int* in_sizes, int n_in,
                              void* d_out, int out_size, void* d_ws, size_t ws_size,
                              hipStream_t stream) {
  const float* z  = (const float*)d_in[0];
  const float* W1 = (const float*)d_in[1];
  const float* b1 = (const float*)d_in[2];
  const float* W2 = (const float*)d_in[3];
  const float* b2 = (const float*)d_in[4];
  const float* W3 = (const float*)d_in[5];
  const float* b3 = (const float*)d_in[6];
  float* xout  = (float*)d_out;
  float* ldout = xout + (size_t)BATCH * DIM;

  char* ws = (char*)d_ws;
  u16* W1h = (u16*)ws;  ws += (size_t)512 * 64 * 2;
  u16* W2h = (u16*)ws;  ws += (size_t)512 * 512 * 2;
  u16* W3h = (u16*)ws;  ws += (size_t)NPAD * HID * 2;
  float* b3p = (float*)ws; ws += (size_t)NPAD * 4;
  // za and part alias (disjoint lifetimes: za consumed by gemm1; part written by gemm3)
  u16* zah  = (u16*)ws;
  float* part = (float*)ws; ws += (size_t)BATCH * 64 * 2;   // 4 MB (part needs 2 MB)
  u16* h1h = (u16*)ws;  ws += (size_t)BATCH * HID * 2;
  u16* h2h = (u16*)ws;  ws += (size_t)BATCH * HID * 2;

  // prep (1688 blocks) + passthrough x-copy (2048 blocks)
  prep_all_v16<<<1688 + 2048, 256, 0, stream>>>(z, W1, W2, W3, b3, zah, W1h, W2h, W3h, b3p, xout);

  // GEMM1: A = za (R=BATCH, rs16=2048), K=64 (NKT=2)
  gemm_relu_v16<2><<<(BATCH / 128) * 4, 256, 0, stream>>>(zah, W1h, b1, h1h, BATCH >> 4);
  // GEMM2: A = h1 (R=BATCH), K=512 (NKT=16)
  gemm_relu_v16<16><<<(BATCH / 128) * 4, 256, 0, stream>>>(h1h, W2h, b2, h2h, BATCH >> 4);
  // GEMM3 + spline
  gemm3_spline_v16<<<(BATCH / 128) * (NPAD / 128), 256, 0, stream>>>(h2h, W3h, b3p, z, xout, part);

  reduce_ld_v16<<<BATCH / 256, 256, 0, stream>>>(part, ldout);
}